// Round 1
// baseline (1599.968 us; speedup 1.0000x reference)
//
#include <hip/hip_runtime.h>
#include <math.h>

// Problem constants (B=4,S=1024 -> T=4096; D=2048; E=16; H=1024; top-2)
#define T_TOK 4096
#define DDIM  2048
#define HDIM  1024
#define NEXP  16
#define CAP   4096   // max tokens per expert (each token picks 2 DISTINCT experts)
#define BM    64
#define BN    64
#define BK    32

typedef __attribute__((ext_vector_type(8))) short  short8;
typedef __attribute__((ext_vector_type(4))) float  floatx4;

__device__ __forceinline__ unsigned short f2bf(float f) {
    unsigned int u = __float_as_uint(f);
    u += 0x7fffu + ((u >> 16) & 1u);   // round-to-nearest-even
    return (unsigned short)(u >> 16);
}

// ---------------------------------------------------------------------------
// Kernel 1: routing. One wave per token: 16 fp32 dots (K=2048), sigmoid,
// top-2 (strict > keeps lower index on ties, matching lax.top_k), normalize,
// atomic-append to per-expert lists.
// ---------------------------------------------------------------------------
__global__ __launch_bounds__(256) void gate_kernel(
    const float* __restrict__ x, const float* __restrict__ Wg,
    const float* __restrict__ bias, int* __restrict__ counts,
    int* __restrict__ tok_list, float* __restrict__ w_list)
{
    int wv   = threadIdx.x >> 6;
    int lane = threadIdx.x & 63;
    int t    = blockIdx.x * 4 + wv;
    const float* xp = x + (size_t)t * DDIM;

    float acc[NEXP];
#pragma unroll
    for (int e = 0; e < NEXP; ++e) acc[e] = 0.f;

    for (int d = lane; d < DDIM; d += 64) {
        float xv = xp[d];
#pragma unroll
        for (int e = 0; e < NEXP; ++e) acc[e] += xv * Wg[e * DDIM + d];
    }
#pragma unroll
    for (int e = 0; e < NEXP; ++e) {
        float v = acc[e];
#pragma unroll
        for (int off = 32; off > 0; off >>= 1) v += __shfl_xor(v, off, 64);
        acc[e] = v;
    }
    if (lane == 0) {
        float s[NEXP];
#pragma unroll
        for (int e = 0; e < NEXP; ++e)
            s[e] = 1.f / (1.f + expf(-(acc[e] + bias[e])));
        int i0 = 0;
#pragma unroll
        for (int e = 1; e < NEXP; ++e) if (s[e] > s[i0]) i0 = e;
        int i1 = (i0 == 0) ? 1 : 0;
        for (int e = 0; e < NEXP; ++e)
            if (e != i0 && s[e] > s[i1]) i1 = e;
        float denom = s[i0] + s[i1] + 1e-6f;
        float w0 = s[i0] / denom;
        float w1 = s[i1] / denom;
        int p0 = atomicAdd(&counts[i0], 1);
        tok_list[i0 * CAP + p0] = t;
        w_list [i0 * CAP + p0] = w0;
        int p1 = atomicAdd(&counts[i1], 1);
        tok_list[i1 * CAP + p1] = t;
        w_list [i1 * CAP + p1] = w1;
    }
}

// ---------------------------------------------------------------------------
// Kernel 2: 16-element prefix sum -> compact h-buffer slot offsets.
// ---------------------------------------------------------------------------
__global__ void scan_kernel(const int* __restrict__ counts, int* __restrict__ offsets)
{
    if (threadIdx.x == 0 && blockIdx.x == 0) {
        int s = 0;
        for (int e = 0; e < NEXP; ++e) { offsets[e] = s; s += counts[e]; }
        offsets[NEXP] = s;   // == 2*T_TOK
    }
}

// ---------------------------------------------------------------------------
// Kernel 3: up-proj. Per (Mtile, expert, Htile): C = silu(Xg @ W1[e]) -> bf16 h.
// A staged fp32->bf16, B (W1, [k][n] in memory) transpose-staged into [n][k].
// 4 waves in 2x2, each computing 32x32 via 2x2 of 16x16x32 bf16 MFMA.
// ---------------------------------------------------------------------------
__global__ __launch_bounds__(256) void up_gemm(
    const float* __restrict__ x, const float* __restrict__ W1,
    const int* __restrict__ counts, const int* __restrict__ offsets,
    const int* __restrict__ tok_list, unsigned short* __restrict__ hbuf)
{
    int e   = blockIdx.y;
    int cnt = counts[e];
    int mt  = blockIdx.x;
    if (mt * BM >= cnt) return;
    int nbase = blockIdx.z * BN;

    __shared__ unsigned short As[BM][BK + 8];
    __shared__ unsigned short Bs[BN][BK + 8];
    __shared__ int toks[BM];

    int tid = threadIdx.x;
    if (tid < BM) {
        int m = mt * BM + tid;
        if (m >= cnt) m = cnt - 1;
        toks[tid] = tok_list[e * CAP + m];
    }
    __syncthreads();

    const float* W1e = W1 + (size_t)e * DDIM * HDIM;
    int lane = tid & 63;
    int wv   = tid >> 6;
    int wm   = (wv & 1) * 32;
    int wn   = (wv >> 1) * 32;
    int fr   = lane & 15;   // fragment row(A)/col(B,D) index
    int fq   = lane >> 4;   // quad

    floatx4 acc[2][2];
#pragma unroll
    for (int i = 0; i < 2; ++i)
#pragma unroll
        for (int j = 0; j < 2; ++j) acc[i][j] = (floatx4){0.f, 0.f, 0.f, 0.f};

    int ar = tid >> 2;        // A row 0..63
    int ak = (tid & 3) * 8;   // A k 0,8,16,24
    int bd = tid >> 3;        // B k-row 0..31
    int bn = (tid & 7) * 8;   // B n 0..56

    const float* xrow = x + (size_t)toks[ar] * DDIM + ak;

    for (int k0 = 0; k0 < DDIM; k0 += BK) {
        float4 a0 = *(const float4*)(xrow + k0);
        float4 a1 = *(const float4*)(xrow + k0 + 4);
        const float* bp = W1e + (size_t)(k0 + bd) * HDIM + nbase + bn;
        float4 b0 = *(const float4*)(bp);
        float4 b1 = *(const float4*)(bp + 4);

        __syncthreads();   // previous iteration's LDS reads done
        short8 av;
        av[0] = (short)f2bf(a0.x); av[1] = (short)f2bf(a0.y);
        av[2] = (short)f2bf(a0.z); av[3] = (short)f2bf(a0.w);
        av[4] = (short)f2bf(a1.x); av[5] = (short)f2bf(a1.y);
        av[6] = (short)f2bf(a1.z); av[7] = (short)f2bf(a1.w);
        *(short8*)&As[ar][ak] = av;
        Bs[bn + 0][bd] = f2bf(b0.x); Bs[bn + 1][bd] = f2bf(b0.y);
        Bs[bn + 2][bd] = f2bf(b0.z); Bs[bn + 3][bd] = f2bf(b0.w);
        Bs[bn + 4][bd] = f2bf(b1.x); Bs[bn + 5][bd] = f2bf(b1.y);
        Bs[bn + 6][bd] = f2bf(b1.z); Bs[bn + 7][bd] = f2bf(b1.w);
        __syncthreads();

        short8 a_frag[2], b_frag[2];
#pragma unroll
        for (int mi = 0; mi < 2; ++mi)
            a_frag[mi] = *(const short8*)&As[wm + mi * 16 + fr][fq * 8];
#pragma unroll
        for (int ni = 0; ni < 2; ++ni)
            b_frag[ni] = *(const short8*)&Bs[wn + ni * 16 + fr][fq * 8];
#pragma unroll
        for (int mi = 0; mi < 2; ++mi)
#pragma unroll
            for (int ni = 0; ni < 2; ++ni)
                acc[mi][ni] = __builtin_amdgcn_mfma_f32_16x16x32_bf16(
                    a_frag[mi], b_frag[ni], acc[mi][ni], 0, 0, 0);
    }

    int hbase = offsets[e];
#pragma unroll
    for (int mi = 0; mi < 2; ++mi) {
#pragma unroll
        for (int r = 0; r < 4; ++r) {
            int row = wm + mi * 16 + fq * 4 + r;
            int m = mt * BM + row;
            if (m < cnt) {
                size_t rowoff = (size_t)(hbase + m) * HDIM + nbase;
#pragma unroll
                for (int ni = 0; ni < 2; ++ni) {
                    float u  = acc[mi][ni][r];
                    float hh = u / (1.f + expf(-u));      // silu
                    hbuf[rowoff + wn + ni * 16 + fr] = f2bf(hh);
                }
            }
        }
    }
}

// ---------------------------------------------------------------------------
// Kernel 4: down-proj. Per (Mtile, expert, Dtile): y = h @ W2[e]; epilogue
// scales by routed weight and atomicAdds into zero-initialized out.
// ---------------------------------------------------------------------------
__global__ __launch_bounds__(256) void down_gemm(
    const unsigned short* __restrict__ hbuf, const float* __restrict__ W2,
    const int* __restrict__ counts, const int* __restrict__ offsets,
    const int* __restrict__ tok_list, const float* __restrict__ w_list,
    float* __restrict__ out)
{
    int e   = blockIdx.y;
    int cnt = counts[e];
    int mt  = blockIdx.x;
    if (mt * BM >= cnt) return;
    int nbase = blockIdx.z * BN;

    __shared__ unsigned short As[BM][BK + 8];
    __shared__ unsigned short Bs[BN][BK + 8];
    __shared__ int   toks[BM];
    __shared__ float wts [BM];

    int tid = threadIdx.x;
    if (tid < BM) {
        int m  = mt * BM + tid;
        int mc = (m >= cnt) ? cnt - 1 : m;
        toks[tid] = tok_list[e * CAP + mc];
        wts [tid] = w_list [e * CAP + mc];
    }
    __syncthreads();

    const float* W2e = W2 + (size_t)e * HDIM * DDIM;
    int hbase = offsets[e];
    int lane = tid & 63;
    int wv   = tid >> 6;
    int wm   = (wv & 1) * 32;
    int wn   = (wv >> 1) * 32;
    int fr   = lane & 15;
    int fq   = lane >> 4;

    floatx4 acc[2][2];
#pragma unroll
    for (int i = 0; i < 2; ++i)
#pragma unroll
        for (int j = 0; j < 2; ++j) acc[i][j] = (floatx4){0.f, 0.f, 0.f, 0.f};

    int ar = tid >> 2;
    int ak = (tid & 3) * 8;
    int bd = tid >> 3;
    int bn = (tid & 7) * 8;

    int m_a = mt * BM + ar;
    if (m_a >= cnt) m_a = cnt - 1;
    const unsigned short* hrow = hbuf + (size_t)(hbase + m_a) * HDIM + ak;

    for (int k0 = 0; k0 < HDIM; k0 += BK) {
        short8 av = *(const short8*)(hrow + k0);
        const float* bp = W2e + (size_t)(k0 + bd) * DDIM + nbase + bn;
        float4 b0 = *(const float4*)(bp);
        float4 b1 = *(const float4*)(bp + 4);

        __syncthreads();
        *(short8*)&As[ar][ak] = av;
        Bs[bn + 0][bd] = f2bf(b0.x); Bs[bn + 1][bd] = f2bf(b0.y);
        Bs[bn + 2][bd] = f2bf(b0.z); Bs[bn + 3][bd] = f2bf(b0.w);
        Bs[bn + 4][bd] = f2bf(b1.x); Bs[bn + 5][bd] = f2bf(b1.y);
        Bs[bn + 6][bd] = f2bf(b1.z); Bs[bn + 7][bd] = f2bf(b1.w);
        __syncthreads();

        short8 a_frag[2], b_frag[2];
#pragma unroll
        for (int mi = 0; mi < 2; ++mi)
            a_frag[mi] = *(const short8*)&As[wm + mi * 16 + fr][fq * 8];
#pragma unroll
        for (int ni = 0; ni < 2; ++ni)
            b_frag[ni] = *(const short8*)&Bs[wn + ni * 16 + fr][fq * 8];
#pragma unroll
        for (int mi = 0; mi < 2; ++mi)
#pragma unroll
            for (int ni = 0; ni < 2; ++ni)
                acc[mi][ni] = __builtin_amdgcn_mfma_f32_16x16x32_bf16(
                    a_frag[mi], b_frag[ni], acc[mi][ni], 0, 0, 0);
    }

#pragma unroll
    for (int mi = 0; mi < 2; ++mi) {
#pragma unroll
        for (int r = 0; r < 4; ++r) {
            int row = wm + mi * 16 + fq * 4 + r;
            int m = mt * BM + row;
            if (m < cnt) {
                float wgt = wts[row];
                size_t obase = (size_t)toks[row] * DDIM + nbase;
#pragma unroll
                for (int ni = 0; ni < 2; ++ni) {
                    atomicAdd(&out[obase + wn + ni * 16 + fr],
                              acc[mi][ni][r] * wgt);
                }
            }
        }
    }
}

// ---------------------------------------------------------------------------
// Workspace layout (bytes):
//   0      : counts[16]          (zeroed each launch)
//   64     : offsets[17]
//   1024   : tok_list[16*4096]   int32   (256 KB)
//   263168 : w_list [16*4096]   fp32    (256 KB)
//   526336 : hbuf   [8192*1024] bf16    (16 MB)
// total ~17.3 MB
// ---------------------------------------------------------------------------
extern "C" void kernel_launch(void* const* d_in, const int* in_sizes, int n_in,
                              void* d_out, int out_size, void* d_ws, size_t ws_size,
                              hipStream_t stream)
{
    const float* x    = (const float*)d_in[0];
    const float* Wg   = (const float*)d_in[1];
    const float* bias = (const float*)d_in[2];
    const float* W1   = (const float*)d_in[3];
    const float* W2   = (const float*)d_in[4];
    float* out = (float*)d_out;

    char* ws = (char*)d_ws;
    int*            counts   = (int*)(ws + 0);
    int*            offsets  = (int*)(ws + 64);
    int*            tok_list = (int*)(ws + 1024);
    float*          w_list   = (float*)(ws + 1024 + 16 * CAP * 4);
    unsigned short* hbuf     = (unsigned short*)(ws + 526336);

    hipMemsetAsync(counts, 0, 64, stream);
    hipMemsetAsync(out, 0, (size_t)T_TOK * DDIM * sizeof(float), stream);

    gate_kernel<<<T_TOK / 4, 256, 0, stream>>>(x, Wg, bias, counts, tok_list, w_list);
    scan_kernel<<<1, 64, 0, stream>>>(counts, offsets);
    up_gemm<<<dim3(CAP / BM, NEXP, HDIM / BN), 256, 0, stream>>>(
        x, W1, counts, offsets, tok_list, hbuf);
    down_gemm<<<dim3(CAP / BM, NEXP, DDIM / BN), 256, 0, stream>>>(
        hbuf, W2, counts, offsets, tok_list, w_list, out);
}

// Round 2
// 1159.040 us; speedup vs baseline: 1.3804x; 1.3804x over previous
//
#include <hip/hip_runtime.h>
#include <math.h>

// Problem constants (B=4,S=1024 -> T=4096; D=2048; E=16; H=1024; top-2)
#define T_TOK 4096
#define DDIM  2048
#define HDIM  1024
#define NEXP  16
#define CAP   4096
#define GBM   128
#define GBN   128
#define GBK   64     // bf16 elems per K-tile

typedef __attribute__((ext_vector_type(8))) short  short8;
typedef __attribute__((ext_vector_type(4))) float  floatx4;

__device__ __forceinline__ unsigned short f2bf(float f) {
    unsigned int u = __float_as_uint(f);
    u += 0x7fffu + ((u >> 16) & 1u);   // round-to-nearest-even
    return (unsigned short)(u >> 16);
}

// async global->LDS 16B: global side may be per-lane scattered; LDS side is
// wave-uniform base + lane*16 (pass the lane-ordered pointer; HW uses lane0's).
__device__ __forceinline__ void gl_lds16(const void* g, void* l) {
    __builtin_amdgcn_global_load_lds(
        (const __attribute__((address_space(1))) unsigned int*)g,
        (__attribute__((address_space(3))) unsigned int*)l,
        16, 0, 0);
}

// ---------------------------------------------------------------------------
// Kernel 1: routing (one wave/token) + emit x in bf16 for GEMM A-staging.
// ---------------------------------------------------------------------------
__global__ __launch_bounds__(256) void gate_kernel(
    const float* __restrict__ x, const float* __restrict__ Wg,
    const float* __restrict__ bias, int* __restrict__ counts,
    int* __restrict__ tok_list, float* __restrict__ w_list,
    unsigned short* __restrict__ xbf)
{
    int wv   = threadIdx.x >> 6;
    int lane = threadIdx.x & 63;
    int t    = blockIdx.x * 4 + wv;
    const float* xp = x + (size_t)t * DDIM;
    unsigned short* xbp = xbf + (size_t)t * DDIM;

    float acc[NEXP];
#pragma unroll
    for (int e = 0; e < NEXP; ++e) acc[e] = 0.f;

    for (int d = lane; d < DDIM; d += 64) {
        float xv = xp[d];
        xbp[d] = f2bf(xv);
#pragma unroll
        for (int e = 0; e < NEXP; ++e) acc[e] += xv * Wg[e * DDIM + d];
    }
#pragma unroll
    for (int e = 0; e < NEXP; ++e) {
        float v = acc[e];
#pragma unroll
        for (int off = 32; off > 0; off >>= 1) v += __shfl_xor(v, off, 64);
        acc[e] = v;
    }
    if (lane == 0) {
        float s[NEXP];
#pragma unroll
        for (int e = 0; e < NEXP; ++e)
            s[e] = 1.f / (1.f + expf(-(acc[e] + bias[e])));
        int i0 = 0;
#pragma unroll
        for (int e = 1; e < NEXP; ++e) if (s[e] > s[i0]) i0 = e;
        int i1 = (i0 == 0) ? 1 : 0;
        for (int e = 0; e < NEXP; ++e)
            if (e != i0 && s[e] > s[i1]) i1 = e;
        float denom = s[i0] + s[i1] + 1e-6f;
        int p0 = atomicAdd(&counts[i0], 1);
        tok_list[i0 * CAP + p0] = t;
        w_list [i0 * CAP + p0] = s[i0] / denom;
        int p1 = atomicAdd(&counts[i1], 1);
        tok_list[i1 * CAP + p1] = t;
        w_list [i1 * CAP + p1] = s[i1] / denom;
    }
}

// ---------------------------------------------------------------------------
// Kernel 2: 16-element prefix sum -> compact h-buffer slot offsets.
// ---------------------------------------------------------------------------
__global__ void scan_kernel(const int* __restrict__ counts, int* __restrict__ offsets)
{
    if (threadIdx.x == 0 && blockIdx.x == 0) {
        int s = 0;
        for (int e = 0; e < NEXP; ++e) { offsets[e] = s; s += counts[e]; }
        offsets[NEXP] = s;
    }
}

// ---------------------------------------------------------------------------
// Kernel 3: convert+transpose weights to bf16 [e][n][k].
//   z <  16: W1 [e][2048][1024] -> W1T [e][1024][2048]
//   z >= 16: W2 [e][1024][2048] -> W2T [e][2048][1024]
// ---------------------------------------------------------------------------
__global__ __launch_bounds__(256) void transpose_w(
    const float* __restrict__ W1, const float* __restrict__ W2,
    unsigned short* __restrict__ W1T, unsigned short* __restrict__ W2T)
{
    int z = blockIdx.z;
    const float* src; unsigned short* dst; int K, N;
    if (z < NEXP) {
        if (blockIdx.y >= 16) return;           // N=1024 -> 16 n-tiles
        K = DDIM; N = HDIM;
        src = W1 + (size_t)z * K * N;
        dst = W1T + (size_t)z * (size_t)N * K;
    } else {
        if (blockIdx.x >= 16) return;           // K=1024 -> 16 k-tiles
        K = HDIM; N = DDIM;
        src = W2 + (size_t)(z - NEXP) * K * N;
        dst = W2T + (size_t)(z - NEXP) * (size_t)N * K;
    }
    int kt = blockIdx.x * 64, nt = blockIdx.y * 64;

    __shared__ __align__(16) unsigned short Tt[64][72];   // pad 8: 144B row, 16B-aligned
    int tid = threadIdx.x;
    int r = tid >> 4, c4 = (tid & 15) * 4;
    const float* s = src + (size_t)kt * N + nt;
#pragma unroll
    for (int i = 0; i < 4; ++i) {
        int rr = r + i * 16;
        float4 v = *(const float4*)(s + (size_t)rr * N + c4);
        Tt[c4 + 0][rr] = f2bf(v.x); Tt[c4 + 1][rr] = f2bf(v.y);
        Tt[c4 + 2][rr] = f2bf(v.z); Tt[c4 + 3][rr] = f2bf(v.w);
    }
    __syncthreads();
    unsigned short* d = dst + (size_t)nt * K + kt;
#pragma unroll
    for (int it = 0; it < 2; ++it) {
        int c = tid + it * 256;
        int n = c >> 3, kc = c & 7;
        short8 v = *(const short8*)&Tt[n][kc * 8];
        *(short8*)(d + (size_t)n * K + kc * 8) = v;
    }
}

// ---------------------------------------------------------------------------
// GEMM kernels: m97-style 128x128x64 bf16 tiles. 4 waves in 2x2, each wave a
// 64x64 C-tile (4x4 frags of 16x16x32). global_load_lds(16B) staging with
// XOR chunk swizzle (kc ^= row&7) -> conflict-spread ds_read_b128.
// LDS chunk s in [0,1024): row = s>>3, stored kc = (s&7)^(row&7).
// ---------------------------------------------------------------------------
__global__ __launch_bounds__(256) void up_gemm(
    const unsigned short* __restrict__ xbf, const unsigned short* __restrict__ W1T,
    const int* __restrict__ counts, const int* __restrict__ offsets,
    const int* __restrict__ tok_list, unsigned short* __restrict__ hbuf)
{
    int e   = blockIdx.y;
    int cnt = counts[e];
    int mt  = blockIdx.x;
    if (mt * GBM >= cnt) return;
    int nbase = blockIdx.z * GBN;

    __shared__ __align__(16) unsigned short As[GBM * GBK];
    __shared__ __align__(16) unsigned short Bs[GBN * GBK];

    int tid = threadIdx.x, lane = tid & 63, wv = tid >> 6;
    int kcL = ((lane & 7) ^ ((lane >> 3) & 7)) * 8;  // swizzled global chunk (elems)
    int hbase = offsets[e];

    const unsigned short* gA[4];
    const unsigned short* gB[4];
#pragma unroll
    for (int j = 0; j < 4; ++j) {
        int row = wv * 32 + j * 8 + (lane >> 3);
        int m = mt * GBM + row; if (m >= cnt) m = cnt - 1;
        int tok = tok_list[e * CAP + m];
        gA[j] = xbf + (size_t)tok * DDIM + kcL;
        gB[j] = W1T + ((size_t)e * HDIM + nbase + row) * DDIM + kcL;
    }
    int fr = lane & 15, fq = lane >> 4;
    int wm = (wv & 1) * 64, wn = (wv >> 1) * 64;

    floatx4 acc[4][4];
#pragma unroll
    for (int i = 0; i < 4; ++i)
#pragma unroll
        for (int j = 0; j < 4; ++j) acc[i][j] = (floatx4){0.f, 0.f, 0.f, 0.f};

    for (int k0 = 0; k0 < DDIM; k0 += GBK) {
        __syncthreads();
#pragma unroll
        for (int j = 0; j < 4; ++j)
            gl_lds16(gA[j] + k0, &As[((wv * 4 + j) * 64 + lane) * 8]);
#pragma unroll
        for (int j = 0; j < 4; ++j)
            gl_lds16(gB[j] + k0, &Bs[((wv * 4 + j) * 64 + lane) * 8]);
        __syncthreads();
#pragma unroll
        for (int ks = 0; ks < 2; ++ks) {
            short8 af[4], bfr[4];
#pragma unroll
            for (int mi = 0; mi < 4; ++mi) {
                int row = wm + mi * 16 + fr;
                int kcs = (ks * 4 + fq) ^ (row & 7);
                af[mi] = *(const short8*)&As[row * GBK + kcs * 8];
            }
#pragma unroll
            for (int ni = 0; ni < 4; ++ni) {
                int row = wn + ni * 16 + fr;
                int kcs = (ks * 4 + fq) ^ (row & 7);
                bfr[ni] = *(const short8*)&Bs[row * GBK + kcs * 8];
            }
#pragma unroll
            for (int mi = 0; mi < 4; ++mi)
#pragma unroll
                for (int ni = 0; ni < 4; ++ni)
                    acc[mi][ni] = __builtin_amdgcn_mfma_f32_16x16x32_bf16(
                        af[mi], bfr[ni], acc[mi][ni], 0, 0, 0);
        }
    }

#pragma unroll
    for (int mi = 0; mi < 4; ++mi) {
#pragma unroll
        for (int r = 0; r < 4; ++r) {
            int row = wm + mi * 16 + fq * 4 + r;
            int m = mt * GBM + row;
            if (m < cnt) {
                size_t ro = (size_t)(hbase + m) * HDIM + nbase + wn;
#pragma unroll
                for (int ni = 0; ni < 4; ++ni) {
                    float u  = acc[mi][ni][r];
                    float hh = u / (1.f + __expf(-u));     // silu
                    hbuf[ro + ni * 16 + fr] = f2bf(hh);
                }
            }
        }
    }
}

__global__ __launch_bounds__(256) void down_gemm(
    const unsigned short* __restrict__ hbuf, const unsigned short* __restrict__ W2T,
    const int* __restrict__ counts, const int* __restrict__ offsets,
    const int* __restrict__ tok_list, const float* __restrict__ w_list,
    float* __restrict__ out)
{
    int e   = blockIdx.y;
    int cnt = counts[e];
    int mt  = blockIdx.x;
    if (mt * GBM >= cnt) return;
    int nbase = blockIdx.z * GBN;

    __shared__ __align__(16) unsigned short As[GBM * GBK];
    __shared__ __align__(16) unsigned short Bs[GBN * GBK];
    __shared__ int   toks[GBM];
    __shared__ float wts [GBM];

    int tid = threadIdx.x, lane = tid & 63, wv = tid >> 6;
    if (tid < GBM) {
        int m  = mt * GBM + tid;
        int mc = (m >= cnt) ? cnt - 1 : m;
        toks[tid] = tok_list[e * CAP + mc];
        wts [tid] = w_list [e * CAP + mc];
    }
    int kcL = ((lane & 7) ^ ((lane >> 3) & 7)) * 8;
    int hbase = offsets[e];

    const unsigned short* gA[4];
    const unsigned short* gB[4];
#pragma unroll
    for (int j = 0; j < 4; ++j) {
        int row = wv * 32 + j * 8 + (lane >> 3);
        int m = mt * GBM + row; if (m >= cnt) m = cnt - 1;
        gA[j] = hbuf + (size_t)(hbase + m) * HDIM + kcL;
        gB[j] = W2T + ((size_t)e * DDIM + nbase + row) * HDIM + kcL;
    }
    int fr = lane & 15, fq = lane >> 4;
    int wm = (wv & 1) * 64, wn = (wv >> 1) * 64;

    floatx4 acc[4][4];
#pragma unroll
    for (int i = 0; i < 4; ++i)
#pragma unroll
        for (int j = 0; j < 4; ++j) acc[i][j] = (floatx4){0.f, 0.f, 0.f, 0.f};

    for (int k0 = 0; k0 < HDIM; k0 += GBK) {
        __syncthreads();
#pragma unroll
        for (int j = 0; j < 4; ++j)
            gl_lds16(gA[j] + k0, &As[((wv * 4 + j) * 64 + lane) * 8]);
#pragma unroll
        for (int j = 0; j < 4; ++j)
            gl_lds16(gB[j] + k0, &Bs[((wv * 4 + j) * 64 + lane) * 8]);
        __syncthreads();
#pragma unroll
        for (int ks = 0; ks < 2; ++ks) {
            short8 af[4], bfr[4];
#pragma unroll
            for (int mi = 0; mi < 4; ++mi) {
                int row = wm + mi * 16 + fr;
                int kcs = (ks * 4 + fq) ^ (row & 7);
                af[mi] = *(const short8*)&As[row * GBK + kcs * 8];
            }
#pragma unroll
            for (int ni = 0; ni < 4; ++ni) {
                int row = wn + ni * 16 + fr;
                int kcs = (ks * 4 + fq) ^ (row & 7);
                bfr[ni] = *(const short8*)&Bs[row * GBK + kcs * 8];
            }
#pragma unroll
            for (int mi = 0; mi < 4; ++mi)
#pragma unroll
                for (int ni = 0; ni < 4; ++ni)
                    acc[mi][ni] = __builtin_amdgcn_mfma_f32_16x16x32_bf16(
                        af[mi], bfr[ni], acc[mi][ni], 0, 0, 0);
        }
    }

#pragma unroll
    for (int mi = 0; mi < 4; ++mi) {
#pragma unroll
        for (int r = 0; r < 4; ++r) {
            int row = wm + mi * 16 + fq * 4 + r;
            int m = mt * GBM + row;
            if (m < cnt) {
                float w = wts[row];
                size_t ob = (size_t)toks[row] * DDIM + nbase + wn;
#pragma unroll
                for (int ni = 0; ni < 4; ++ni)
                    atomicAdd(&out[ob + ni * 16 + fr], acc[mi][ni][r] * w);
            }
        }
    }
}

// ---------------------------------------------------------------------------
// Workspace layout (bytes):
//   0          counts[16]
//   256        offsets[17]
//   1024       tok_list  16*4096*4   = 256 KB
//   263168     w_list    16*4096*4   = 256 KB
//   525312     xbf       4096*2048*2 = 16 MB
//   17302528   hbuf      8192*1024*2 = 16 MB
//   34079744   W1T bf16  16*1024*2048*2 = 64 MB
//   101188608  W2T bf16  16*2048*1024*2 = 64 MB
//   total ~168.3 MB
// ---------------------------------------------------------------------------
extern "C" void kernel_launch(void* const* d_in, const int* in_sizes, int n_in,
                              void* d_out, int out_size, void* d_ws, size_t ws_size,
                              hipStream_t stream)
{
    const float* x    = (const float*)d_in[0];
    const float* Wg   = (const float*)d_in[1];
    const float* bias = (const float*)d_in[2];
    const float* W1   = (const float*)d_in[3];
    const float* W2   = (const float*)d_in[4];
    float* out = (float*)d_out;

    char* ws = (char*)d_ws;
    int*            counts   = (int*)(ws + 0);
    int*            offsets  = (int*)(ws + 256);
    int*            tok_list = (int*)(ws + 1024);
    float*          w_list   = (float*)(ws + 263168);
    unsigned short* xbf      = (unsigned short*)(ws + 525312);
    unsigned short* hbuf     = (unsigned short*)(ws + 17302528);
    unsigned short* W1T      = (unsigned short*)(ws + 34079744);
    unsigned short* W2T      = (unsigned short*)(ws + 101188608);

    hipMemsetAsync(counts, 0, 64, stream);
    hipMemsetAsync(out, 0, (size_t)T_TOK * DDIM * sizeof(float), stream);

    gate_kernel<<<T_TOK / 4, 256, 0, stream>>>(x, Wg, bias, counts, tok_list, w_list, xbf);
    scan_kernel<<<1, 64, 0, stream>>>(counts, offsets);
    transpose_w<<<dim3(32, 32, 32), 256, 0, stream>>>(W1, W2, W1T, W2T);
    up_gemm<<<dim3(CAP / GBM, NEXP, HDIM / GBN), 256, 0, stream>>>(
        xbf, W1T, counts, offsets, tok_list, hbuf);
    down_gemm<<<dim3(CAP / GBM, NEXP, DDIM / GBN), 256, 0, stream>>>(
        hbuf, W2T, counts, offsets, tok_list, w_list, out);
}

// Round 3
// 688.878 us; speedup vs baseline: 2.3226x; 1.6825x over previous
//
#include <hip/hip_runtime.h>
#include <math.h>

// Problem constants (B=4,S=1024 -> T=4096; D=2048; E=16; H=1024; top-2)
#define T_TOK 4096
#define DDIM  2048
#define HDIM  1024
#define NEXP  16
#define CAP   4096
#define GBM   128
#define GBN   128
#define GBK   64     // bf16 elems per K-tile
#define MAX_TILES 80 // sum ceil(cnt_e/128) <= 8192/128 + 16

typedef __attribute__((ext_vector_type(8))) short  short8;
typedef __attribute__((ext_vector_type(4))) float  floatx4;

__device__ __forceinline__ unsigned short f2bf(float f) {
    unsigned int u = __float_as_uint(f);
    u += 0x7fffu + ((u >> 16) & 1u);   // round-to-nearest-even
    return (unsigned short)(u >> 16);
}

__device__ __forceinline__ void gl_lds16(const void* g, void* l) {
    __builtin_amdgcn_global_load_lds(
        (const __attribute__((address_space(1))) unsigned int*)g,
        (__attribute__((address_space(3))) unsigned int*)l,
        16, 0, 0);
}

// ---------------------------------------------------------------------------
// Kernel 1: routing (one wave/token) + emit x in bf16 for GEMM A-staging.
// ---------------------------------------------------------------------------
__global__ __launch_bounds__(256) void gate_kernel(
    const float* __restrict__ x, const float* __restrict__ Wg,
    const float* __restrict__ bias, int* __restrict__ counts,
    int* __restrict__ tok_list, float* __restrict__ w_list,
    unsigned short* __restrict__ xbf)
{
    int wv   = threadIdx.x >> 6;
    int lane = threadIdx.x & 63;
    int t    = blockIdx.x * 4 + wv;
    const float* xp = x + (size_t)t * DDIM;
    unsigned short* xbp = xbf + (size_t)t * DDIM;

    float acc[NEXP];
#pragma unroll
    for (int e = 0; e < NEXP; ++e) acc[e] = 0.f;

    for (int d = lane; d < DDIM; d += 64) {
        float xv = xp[d];
        xbp[d] = f2bf(xv);
#pragma unroll
        for (int e = 0; e < NEXP; ++e) acc[e] += xv * Wg[e * DDIM + d];
    }
#pragma unroll
    for (int e = 0; e < NEXP; ++e) {
        float v = acc[e];
#pragma unroll
        for (int off = 32; off > 0; off >>= 1) v += __shfl_xor(v, off, 64);
        acc[e] = v;
    }
    if (lane == 0) {
        float s[NEXP];
#pragma unroll
        for (int e = 0; e < NEXP; ++e)
            s[e] = 1.f / (1.f + expf(-(acc[e] + bias[e])));
        int i0 = 0;
#pragma unroll
        for (int e = 1; e < NEXP; ++e) if (s[e] > s[i0]) i0 = e;
        int i1 = (i0 == 0) ? 1 : 0;
        for (int e = 0; e < NEXP; ++e)
            if (e != i0 && s[e] > s[i1]) i1 = e;
        float denom = s[i0] + s[i1] + 1e-6f;
        int p0 = atomicAdd(&counts[i0], 1);
        tok_list[i0 * CAP + p0] = t;
        w_list [i0 * CAP + p0] = s[i0] / denom;
        int p1 = atomicAdd(&counts[i1], 1);
        tok_list[i1 * CAP + p1] = t;
        w_list [i1 * CAP + p1] = s[i1] / denom;
    }
}

// ---------------------------------------------------------------------------
// Kernel 2: prefix sum + dense (expert, mt) tile work-list.
// ---------------------------------------------------------------------------
__global__ void scan_kernel(const int* __restrict__ counts, int* __restrict__ offsets,
                            int* __restrict__ ntiles, int* __restrict__ tile_e,
                            int* __restrict__ tile_mt)
{
    if (threadIdx.x == 0 && blockIdx.x == 0) {
        int s = 0, nt = 0;
        for (int e = 0; e < NEXP; ++e) {
            offsets[e] = s;
            int c = counts[e];
            s += c;
            for (int mt = 0; mt * GBM < c; ++mt) {
                tile_e[nt] = e; tile_mt[nt] = mt; ++nt;
            }
        }
        offsets[NEXP] = s;
        *ntiles = nt;
    }
}

// ---------------------------------------------------------------------------
// Kernel 3: convert+transpose weights to bf16 [e][n][k]. All blocks live:
//   z <  16: W1 [e][2048][1024] -> W1T [e][1024][2048]  kt=y(32) nt=x(16)
//   z >= 16: W2 [e][1024][2048] -> W2T [e][2048][1024]  kt=x(16) nt=y(32)
// ---------------------------------------------------------------------------
__global__ __launch_bounds__(256) void transpose_w(
    const float* __restrict__ W1, const float* __restrict__ W2,
    unsigned short* __restrict__ W1T, unsigned short* __restrict__ W2T)
{
    int z = blockIdx.z;
    const float* src; unsigned short* dst; int K, N, kt, nt;
    if (z < NEXP) {
        K = DDIM; N = HDIM;
        src = W1 + (size_t)z * K * N;
        dst = W1T + (size_t)z * (size_t)N * K;
        kt = blockIdx.y * 64; nt = blockIdx.x * 64;
    } else {
        K = HDIM; N = DDIM;
        src = W2 + (size_t)(z - NEXP) * K * N;
        dst = W2T + (size_t)(z - NEXP) * (size_t)N * K;
        kt = blockIdx.x * 64; nt = blockIdx.y * 64;
    }

    __shared__ __align__(16) unsigned short Tt[64][72];
    int tid = threadIdx.x;
    int r = tid >> 4, c4 = (tid & 15) * 4;
    const float* s = src + (size_t)kt * N + nt;
#pragma unroll
    for (int i = 0; i < 4; ++i) {
        int rr = r + i * 16;
        float4 v = *(const float4*)(s + (size_t)rr * N + c4);
        Tt[c4 + 0][rr] = f2bf(v.x); Tt[c4 + 1][rr] = f2bf(v.y);
        Tt[c4 + 2][rr] = f2bf(v.z); Tt[c4 + 3][rr] = f2bf(v.w);
    }
    __syncthreads();
    unsigned short* d = dst + (size_t)nt * K + kt;
#pragma unroll
    for (int it = 0; it < 2; ++it) {
        int c = tid + it * 256;
        int n = c >> 3, kc = c & 7;
        short8 v = *(const short8*)&Tt[n][kc * 8];
        *(short8*)(d + (size_t)n * K + kc * 8) = v;
    }
}

// ---------------------------------------------------------------------------
// GEMMs: 128x128x64 bf16 tiles, dense work-list in x, ping-pong LDS dbuf.
// Per K-iter: barrier (drains prev issue, overlapped with prev compute),
// issue next tile's global_load_lds, compute current from the other buffer.
// ---------------------------------------------------------------------------
__global__ __launch_bounds__(256) void up_gemm(
    const unsigned short* __restrict__ xbf, const unsigned short* __restrict__ W1T,
    const int* __restrict__ counts, const int* __restrict__ offsets,
    const int* __restrict__ ntiles, const int* __restrict__ tile_e,
    const int* __restrict__ tile_mt,
    const int* __restrict__ tok_list, unsigned short* __restrict__ hbuf)
{
    int idx = blockIdx.x;
    if (idx >= *ntiles) return;
    int e   = tile_e[idx];
    int mt  = tile_mt[idx];
    int cnt = counts[e];
    int nbase = blockIdx.y * GBN;

    __shared__ __align__(16) unsigned short As[2][GBM * GBK];
    __shared__ __align__(16) unsigned short Bs[2][GBN * GBK];

    int tid = threadIdx.x, lane = tid & 63, wv = tid >> 6;
    int kcL = ((lane & 7) ^ ((lane >> 3) & 7)) * 8;
    int hbase = offsets[e];

    const unsigned short* gA[4];
    const unsigned short* gB[4];
#pragma unroll
    for (int j = 0; j < 4; ++j) {
        int row = wv * 32 + j * 8 + (lane >> 3);
        int m = mt * GBM + row; if (m >= cnt) m = cnt - 1;
        int tok = tok_list[e * CAP + m];
        gA[j] = xbf + (size_t)tok * DDIM + kcL;
        gB[j] = W1T + ((size_t)e * HDIM + nbase + row) * DDIM + kcL;
    }
    int fr = lane & 15, fq = lane >> 4;
    int wm = (wv & 1) * 64, wn = (wv >> 1) * 64;

    floatx4 acc[4][4];
#pragma unroll
    for (int i = 0; i < 4; ++i)
#pragma unroll
        for (int j = 0; j < 4; ++j) acc[i][j] = (floatx4){0.f, 0.f, 0.f, 0.f};

    // prologue: stage k-tile 0 into buffer 0
#pragma unroll
    for (int j = 0; j < 4; ++j)
        gl_lds16(gA[j], &As[0][((wv * 4 + j) * 64 + lane) * 8]);
#pragma unroll
    for (int j = 0; j < 4; ++j)
        gl_lds16(gB[j], &Bs[0][((wv * 4 + j) * 64 + lane) * 8]);

    const int NK = DDIM / GBK;
    for (int i = 0; i < NK; ++i) {
        int cur = i & 1, nxt = cur ^ 1;
        __syncthreads();               // buf[cur] loads complete; buf[nxt] free
        if (i + 1 < NK) {
            int k0 = (i + 1) * GBK;
#pragma unroll
            for (int j = 0; j < 4; ++j)
                gl_lds16(gA[j] + k0, &As[nxt][((wv * 4 + j) * 64 + lane) * 8]);
#pragma unroll
            for (int j = 0; j < 4; ++j)
                gl_lds16(gB[j] + k0, &Bs[nxt][((wv * 4 + j) * 64 + lane) * 8]);
        }
#pragma unroll
        for (int ks = 0; ks < 2; ++ks) {
            short8 af[4], bfr[4];
#pragma unroll
            for (int mi = 0; mi < 4; ++mi) {
                int row = wm + mi * 16 + fr;
                int kcs = (ks * 4 + fq) ^ (row & 7);
                af[mi] = *(const short8*)&As[cur][row * GBK + kcs * 8];
            }
#pragma unroll
            for (int ni = 0; ni < 4; ++ni) {
                int row = wn + ni * 16 + fr;
                int kcs = (ks * 4 + fq) ^ (row & 7);
                bfr[ni] = *(const short8*)&Bs[cur][row * GBK + kcs * 8];
            }
#pragma unroll
            for (int mi = 0; mi < 4; ++mi)
#pragma unroll
                for (int ni = 0; ni < 4; ++ni)
                    acc[mi][ni] = __builtin_amdgcn_mfma_f32_16x16x32_bf16(
                        af[mi], bfr[ni], acc[mi][ni], 0, 0, 0);
        }
    }

#pragma unroll
    for (int mi = 0; mi < 4; ++mi) {
#pragma unroll
        for (int r = 0; r < 4; ++r) {
            int row = wm + mi * 16 + fq * 4 + r;
            int m = mt * GBM + row;
            if (m < cnt) {
                size_t ro = (size_t)(hbase + m) * HDIM + nbase + wn;
#pragma unroll
                for (int ni = 0; ni < 4; ++ni) {
                    float u  = acc[mi][ni][r];
                    float hh = u / (1.f + __expf(-u));     // silu
                    hbuf[ro + ni * 16 + fr] = f2bf(hh);
                }
            }
        }
    }
}

__global__ __launch_bounds__(256) void down_gemm(
    const unsigned short* __restrict__ hbuf, const unsigned short* __restrict__ W2T,
    const int* __restrict__ counts, const int* __restrict__ offsets,
    const int* __restrict__ ntiles, const int* __restrict__ tile_e,
    const int* __restrict__ tile_mt,
    const int* __restrict__ tok_list, const float* __restrict__ w_list,
    float* __restrict__ out)
{
    int idx = blockIdx.x;
    if (idx >= *ntiles) return;
    int e   = tile_e[idx];
    int mt  = tile_mt[idx];
    int cnt = counts[e];
    int nbase = blockIdx.y * GBN;

    __shared__ __align__(16) unsigned short As[2][GBM * GBK];
    __shared__ __align__(16) unsigned short Bs[2][GBN * GBK];
    __shared__ int   toks[GBM];
    __shared__ float wts [GBM];

    int tid = threadIdx.x, lane = tid & 63, wv = tid >> 6;
    if (tid < GBM) {
        int m  = mt * GBM + tid;
        int mc = (m >= cnt) ? cnt - 1 : m;
        toks[tid] = tok_list[e * CAP + mc];
        wts [tid] = w_list [e * CAP + mc];
    }
    int kcL = ((lane & 7) ^ ((lane >> 3) & 7)) * 8;
    int hbase = offsets[e];

    const unsigned short* gA[4];
    const unsigned short* gB[4];
#pragma unroll
    for (int j = 0; j < 4; ++j) {
        int row = wv * 32 + j * 8 + (lane >> 3);
        int m = mt * GBM + row; if (m >= cnt) m = cnt - 1;
        gA[j] = hbuf + (size_t)(hbase + m) * HDIM + kcL;
        gB[j] = W2T + ((size_t)e * DDIM + nbase + row) * HDIM + kcL;
    }
    int fr = lane & 15, fq = lane >> 4;
    int wm = (wv & 1) * 64, wn = (wv >> 1) * 64;

    floatx4 acc[4][4];
#pragma unroll
    for (int i = 0; i < 4; ++i)
#pragma unroll
        for (int j = 0; j < 4; ++j) acc[i][j] = (floatx4){0.f, 0.f, 0.f, 0.f};

#pragma unroll
    for (int j = 0; j < 4; ++j)
        gl_lds16(gA[j], &As[0][((wv * 4 + j) * 64 + lane) * 8]);
#pragma unroll
    for (int j = 0; j < 4; ++j)
        gl_lds16(gB[j], &Bs[0][((wv * 4 + j) * 64 + lane) * 8]);

    const int NK = HDIM / GBK;
    for (int i = 0; i < NK; ++i) {
        int cur = i & 1, nxt = cur ^ 1;
        __syncthreads();
        if (i + 1 < NK) {
            int k0 = (i + 1) * GBK;
#pragma unroll
            for (int j = 0; j < 4; ++j)
                gl_lds16(gA[j] + k0, &As[nxt][((wv * 4 + j) * 64 + lane) * 8]);
#pragma unroll
            for (int j = 0; j < 4; ++j)
                gl_lds16(gB[j] + k0, &Bs[nxt][((wv * 4 + j) * 64 + lane) * 8]);
        }
#pragma unroll
        for (int ks = 0; ks < 2; ++ks) {
            short8 af[4], bfr[4];
#pragma unroll
            for (int mi = 0; mi < 4; ++mi) {
                int row = wm + mi * 16 + fr;
                int kcs = (ks * 4 + fq) ^ (row & 7);
                af[mi] = *(const short8*)&As[cur][row * GBK + kcs * 8];
            }
#pragma unroll
            for (int ni = 0; ni < 4; ++ni) {
                int row = wn + ni * 16 + fr;
                int kcs = (ks * 4 + fq) ^ (row & 7);
                bfr[ni] = *(const short8*)&Bs[cur][row * GBK + kcs * 8];
            }
#pragma unroll
            for (int mi = 0; mi < 4; ++mi)
#pragma unroll
                for (int ni = 0; ni < 4; ++ni)
                    acc[mi][ni] = __builtin_amdgcn_mfma_f32_16x16x32_bf16(
                        af[mi], bfr[ni], acc[mi][ni], 0, 0, 0);
        }
    }

#pragma unroll
    for (int mi = 0; mi < 4; ++mi) {
#pragma unroll
        for (int r = 0; r < 4; ++r) {
            int row = wm + mi * 16 + fq * 4 + r;
            int m = mt * GBM + row;
            if (m < cnt) {
                float w = wts[row];
                size_t ob = (size_t)toks[row] * DDIM + nbase + wn;
#pragma unroll
                for (int ni = 0; ni < 4; ++ni)
                    atomicAdd(&out[ob + ni * 16 + fr], acc[mi][ni][r] * w);
            }
        }
    }
}

// ---------------------------------------------------------------------------
// Workspace layout (bytes):
//   0         counts[16]
//   256       offsets[17]
//   512       ntiles + tile_e[80] + tile_mt[80]
//   2048      tok_list  256 KB
//   264192    w_list    256 KB
//   526336    xbf       16 MB
//   17303552  hbuf      16 MB
//   34080768  W1T       64 MB
//   101189632 W2T       64 MB   -> total ~168.3 MB
// ---------------------------------------------------------------------------
extern "C" void kernel_launch(void* const* d_in, const int* in_sizes, int n_in,
                              void* d_out, int out_size, void* d_ws, size_t ws_size,
                              hipStream_t stream)
{
    const float* x    = (const float*)d_in[0];
    const float* Wg   = (const float*)d_in[1];
    const float* bias = (const float*)d_in[2];
    const float* W1   = (const float*)d_in[3];
    const float* W2   = (const float*)d_in[4];
    float* out = (float*)d_out;

    char* ws = (char*)d_ws;
    int*            counts   = (int*)(ws + 0);
    int*            offsets  = (int*)(ws + 256);
    int*            ntiles   = (int*)(ws + 512);
    int*            tile_e   = (int*)(ws + 512 + 4);
    int*            tile_mt  = (int*)(ws + 512 + 4 + MAX_TILES * 4);
    int*            tok_list = (int*)(ws + 2048);
    float*          w_list   = (float*)(ws + 264192);
    unsigned short* xbf      = (unsigned short*)(ws + 526336);
    unsigned short* hbuf     = (unsigned short*)(ws + 17303552);
    unsigned short* W1T      = (unsigned short*)(ws + 34080768);
    unsigned short* W2T      = (unsigned short*)(ws + 101189632);

    hipMemsetAsync(counts, 0, 64, stream);
    hipMemsetAsync(out, 0, (size_t)T_TOK * DDIM * sizeof(float), stream);

    gate_kernel<<<T_TOK / 4, 256, 0, stream>>>(x, Wg, bias, counts, tok_list, w_list, xbf);
    scan_kernel<<<1, 64, 0, stream>>>(counts, offsets, ntiles, tile_e, tile_mt);
    transpose_w<<<dim3(16, 32, 32), 256, 0, stream>>>(W1, W2, W1T, W2T);
    up_gemm<<<dim3(MAX_TILES, HDIM / GBN), 256, 0, stream>>>(
        xbf, W1T, counts, offsets, ntiles, tile_e, tile_mt, tok_list, hbuf);
    down_gemm<<<dim3(MAX_TILES, DDIM / GBN), 256, 0, stream>>>(
        hbuf, W2T, counts, offsets, ntiles, tile_e, tile_mt, tok_list, w_list, out);
}

// Round 4
// 652.852 us; speedup vs baseline: 2.4507x; 1.0552x over previous
//
#include <hip/hip_runtime.h>
#include <math.h>

// Problem constants (B=4,S=1024 -> T=4096; D=2048; E=16; H=1024; top-2)
#define T_TOK 4096
#define DDIM  2048
#define HDIM  1024
#define NEXP  16
#define CAP   4096
#define GBM   128
#define GBN   128
#define GBK   64     // bf16 elems per K-tile
#define MAX_TILES 80 // sum ceil(cnt_e/128) <= 8192/128 + 16

typedef __attribute__((ext_vector_type(8))) short  short8;
typedef __attribute__((ext_vector_type(4))) float  floatx4;

__device__ __forceinline__ unsigned short f2bf(float f) {
    unsigned int u = __float_as_uint(f);
    u += 0x7fffu + ((u >> 16) & 1u);   // round-to-nearest-even
    return (unsigned short)(u >> 16);
}
__device__ __forceinline__ float bf2f(unsigned short u) {
    return __uint_as_float((unsigned int)u << 16);
}

__device__ __forceinline__ void gl_lds16(const void* g, void* l) {
    __builtin_amdgcn_global_load_lds(
        (const __attribute__((address_space(1))) unsigned int*)g,
        (__attribute__((address_space(3))) unsigned int*)l,
        16, 0, 0);
}

// ---------------------------------------------------------------------------
// prep_kernel: z<16 -> W1 transpose; 16<=z<32 -> W2 transpose; z in {32,33}
// -> gating (1024 blocks, 4 tokens each). Transpose is HBM-bound, gate is
// L1/issue-bound -> co-resident overlap instead of serial 65+146 us.
// ---------------------------------------------------------------------------
__global__ __launch_bounds__(256) void prep_kernel(
    const float* __restrict__ x, const float* __restrict__ Wg,
    const float* __restrict__ bias,
    const float* __restrict__ W1, const float* __restrict__ W2,
    unsigned short* __restrict__ W1T, unsigned short* __restrict__ W2T,
    int* __restrict__ counts, int* __restrict__ tok_list,
    int4* __restrict__ tinfo, float2* __restrict__ wcomb,
    unsigned short* __restrict__ xbf)
{
    __shared__ __align__(16) unsigned short Tt[64][72];
    int z = blockIdx.z;

    if (z < 32) {
        // ---- weight convert+transpose to bf16 [e][n][k] ----
        const float* src; unsigned short* dst; int K, N, kt, nt;
        if (z < NEXP) {
            K = DDIM; N = HDIM;
            src = W1 + (size_t)z * K * N;
            dst = W1T + (size_t)z * (size_t)N * K;
            kt = blockIdx.y * 64; nt = blockIdx.x * 64;
        } else {
            K = HDIM; N = DDIM;
            src = W2 + (size_t)(z - NEXP) * K * N;
            dst = W2T + (size_t)(z - NEXP) * (size_t)N * K;
            kt = blockIdx.x * 64; nt = blockIdx.y * 64;
        }
        int tid = threadIdx.x;
        int r = tid >> 4, c4 = (tid & 15) * 4;
        const float* s = src + (size_t)kt * N + nt;
#pragma unroll
        for (int i = 0; i < 4; ++i) {
            int rr = r + i * 16;
            float4 v = *(const float4*)(s + (size_t)rr * N + c4);
            Tt[c4 + 0][rr] = f2bf(v.x); Tt[c4 + 1][rr] = f2bf(v.y);
            Tt[c4 + 2][rr] = f2bf(v.z); Tt[c4 + 3][rr] = f2bf(v.w);
        }
        __syncthreads();
        unsigned short* d = dst + (size_t)nt * K + kt;
#pragma unroll
        for (int it = 0; it < 2; ++it) {
            int c = tid + it * 256;
            int n = c >> 3, kc = c & 7;
            short8 v = *(const short8*)&Tt[n][kc * 8];
            *(short8*)(d + (size_t)n * K + kc * 8) = v;
        }
        return;
    }

    // ---- gating: one wave per token, float4 loads ----
    int tb   = (z - 32) * 512 + blockIdx.y * 16 + blockIdx.x;   // 0..1023
    int wv   = threadIdx.x >> 6;
    int lane = threadIdx.x & 63;
    int t    = tb * 4 + wv;

    const float4* xp4 = (const float4*)x + (size_t)t * (DDIM / 4);
    ushort4* xbp4 = (ushort4*)(xbf + (size_t)t * DDIM);
    const float4* wg4 = (const float4*)Wg;

    float acc[NEXP];
#pragma unroll
    for (int e = 0; e < NEXP; ++e) acc[e] = 0.f;

    for (int it = 0; it < DDIM / 4 / 64; ++it) {
        int d4 = it * 64 + lane;
        float4 xv = xp4[d4];
        ushort4 xs;
        xs.x = f2bf(xv.x); xs.y = f2bf(xv.y);
        xs.z = f2bf(xv.z); xs.w = f2bf(xv.w);
        xbp4[d4] = xs;
#pragma unroll
        for (int e = 0; e < NEXP; ++e) {
            float4 wvv = wg4[e * (DDIM / 4) + d4];
            acc[e] += xv.x * wvv.x + xv.y * wvv.y + xv.z * wvv.z + xv.w * wvv.w;
        }
    }
#pragma unroll
    for (int e = 0; e < NEXP; ++e) {
        float v = acc[e];
#pragma unroll
        for (int off = 32; off > 0; off >>= 1) v += __shfl_xor(v, off, 64);
        acc[e] = v;
    }
    if (lane == 0) {
        float s[NEXP];
#pragma unroll
        for (int e = 0; e < NEXP; ++e)
            s[e] = 1.f / (1.f + expf(-(acc[e] + bias[e])));
        int i0 = 0;
#pragma unroll
        for (int e = 1; e < NEXP; ++e) if (s[e] > s[i0]) i0 = e;
        int i1 = (i0 == 0) ? 1 : 0;
        for (int e = 0; e < NEXP; ++e)
            if (e != i0 && s[e] > s[i1]) i1 = e;
        float denom = s[i0] + s[i1] + 1e-6f;
        int p0 = atomicAdd(&counts[i0], 1);
        tok_list[i0 * CAP + p0] = t;
        int p1 = atomicAdd(&counts[i1], 1);
        tok_list[i1 * CAP + p1] = t;
        tinfo[t] = make_int4(i0, p0, i1, p1);
        wcomb[t] = make_float2(s[i0] / denom, s[i1] / denom);
    }
}

// ---------------------------------------------------------------------------
// scan: prefix sum + dense (expert, mt) tile work-list.
// ---------------------------------------------------------------------------
__global__ void scan_kernel(const int* __restrict__ counts, int* __restrict__ offsets,
                            int* __restrict__ ntiles, int* __restrict__ tile_e,
                            int* __restrict__ tile_mt)
{
    if (threadIdx.x == 0 && blockIdx.x == 0) {
        int s = 0, nt = 0;
        for (int e = 0; e < NEXP; ++e) {
            offsets[e] = s;
            int c = counts[e];
            s += c;
            for (int mt = 0; mt * GBM < c; ++mt) {
                tile_e[nt] = e; tile_mt[nt] = mt; ++nt;
            }
        }
        offsets[NEXP] = s;
        *ntiles = nt;
    }
}

// ---------------------------------------------------------------------------
// up_gemm: h = silu(Xg @ W1T^T) -> bf16 hbuf. 128x128x64 tiles, ping-pong
// LDS dbuf, global_load_lds(16B), XOR chunk swizzle.
// ---------------------------------------------------------------------------
__global__ __launch_bounds__(256) void up_gemm(
    const unsigned short* __restrict__ xbf, const unsigned short* __restrict__ W1T,
    const int* __restrict__ counts, const int* __restrict__ offsets,
    const int* __restrict__ ntiles, const int* __restrict__ tile_e,
    const int* __restrict__ tile_mt,
    const int* __restrict__ tok_list, unsigned short* __restrict__ hbuf)
{
    int idx = blockIdx.x;
    if (idx >= *ntiles) return;
    int e   = tile_e[idx];
    int mt  = tile_mt[idx];
    int cnt = counts[e];
    int nbase = blockIdx.y * GBN;

    __shared__ __align__(16) unsigned short As[2][GBM * GBK];
    __shared__ __align__(16) unsigned short Bs[2][GBN * GBK];

    int tid = threadIdx.x, lane = tid & 63, wv = tid >> 6;
    int kcL = ((lane & 7) ^ ((lane >> 3) & 7)) * 8;
    int hbase = offsets[e];

    const unsigned short* gA[4];
    const unsigned short* gB[4];
#pragma unroll
    for (int j = 0; j < 4; ++j) {
        int row = wv * 32 + j * 8 + (lane >> 3);
        int m = mt * GBM + row; if (m >= cnt) m = cnt - 1;
        int tok = tok_list[e * CAP + m];
        gA[j] = xbf + (size_t)tok * DDIM + kcL;
        gB[j] = W1T + ((size_t)e * HDIM + nbase + row) * DDIM + kcL;
    }
    int fr = lane & 15, fq = lane >> 4;
    int wm = (wv & 1) * 64, wn = (wv >> 1) * 64;

    floatx4 acc[4][4];
#pragma unroll
    for (int i = 0; i < 4; ++i)
#pragma unroll
        for (int j = 0; j < 4; ++j) acc[i][j] = (floatx4){0.f, 0.f, 0.f, 0.f};

#pragma unroll
    for (int j = 0; j < 4; ++j)
        gl_lds16(gA[j], &As[0][((wv * 4 + j) * 64 + lane) * 8]);
#pragma unroll
    for (int j = 0; j < 4; ++j)
        gl_lds16(gB[j], &Bs[0][((wv * 4 + j) * 64 + lane) * 8]);

    const int NK = DDIM / GBK;
    for (int i = 0; i < NK; ++i) {
        int cur = i & 1, nxt = cur ^ 1;
        __syncthreads();
        if (i + 1 < NK) {
            int k0 = (i + 1) * GBK;
#pragma unroll
            for (int j = 0; j < 4; ++j)
                gl_lds16(gA[j] + k0, &As[nxt][((wv * 4 + j) * 64 + lane) * 8]);
#pragma unroll
            for (int j = 0; j < 4; ++j)
                gl_lds16(gB[j] + k0, &Bs[nxt][((wv * 4 + j) * 64 + lane) * 8]);
        }
#pragma unroll
        for (int ks = 0; ks < 2; ++ks) {
            short8 af[4], bfr[4];
#pragma unroll
            for (int mi = 0; mi < 4; ++mi) {
                int row = wm + mi * 16 + fr;
                int kcs = (ks * 4 + fq) ^ (row & 7);
                af[mi] = *(const short8*)&As[cur][row * GBK + kcs * 8];
            }
#pragma unroll
            for (int ni = 0; ni < 4; ++ni) {
                int row = wn + ni * 16 + fr;
                int kcs = (ks * 4 + fq) ^ (row & 7);
                bfr[ni] = *(const short8*)&Bs[cur][row * GBK + kcs * 8];
            }
#pragma unroll
            for (int mi = 0; mi < 4; ++mi)
#pragma unroll
                for (int ni = 0; ni < 4; ++ni)
                    acc[mi][ni] = __builtin_amdgcn_mfma_f32_16x16x32_bf16(
                        af[mi], bfr[ni], acc[mi][ni], 0, 0, 0);
        }
    }

#pragma unroll
    for (int mi = 0; mi < 4; ++mi) {
#pragma unroll
        for (int r = 0; r < 4; ++r) {
            int row = wm + mi * 16 + fq * 4 + r;
            int m = mt * GBM + row;
            if (m < cnt) {
                size_t ro = (size_t)(hbase + m) * HDIM + nbase + wn;
#pragma unroll
                for (int ni = 0; ni < 4; ++ni) {
                    float u  = acc[mi][ni][r];
                    float hh = u / (1.f + __expf(-u));     // silu
                    hbuf[ro + ni * 16 + fr] = f2bf(hh);
                }
            }
        }
    }
}

// ---------------------------------------------------------------------------
// down_gemm: y = h @ W2T^T -> bf16 ybuf (plain stores, no atomics).
// ---------------------------------------------------------------------------
__global__ __launch_bounds__(256) void down_gemm(
    const unsigned short* __restrict__ hbuf, const unsigned short* __restrict__ W2T,
    const int* __restrict__ counts, const int* __restrict__ offsets,
    const int* __restrict__ ntiles, const int* __restrict__ tile_e,
    const int* __restrict__ tile_mt,
    unsigned short* __restrict__ ybuf)
{
    int idx = blockIdx.x;
    if (idx >= *ntiles) return;
    int e   = tile_e[idx];
    int mt  = tile_mt[idx];
    int cnt = counts[e];
    int nbase = blockIdx.y * GBN;

    __shared__ __align__(16) unsigned short As[2][GBM * GBK];
    __shared__ __align__(16) unsigned short Bs[2][GBN * GBK];

    int tid = threadIdx.x, lane = tid & 63, wv = tid >> 6;
    int kcL = ((lane & 7) ^ ((lane >> 3) & 7)) * 8;
    int hbase = offsets[e];

    const unsigned short* gA[4];
    const unsigned short* gB[4];
#pragma unroll
    for (int j = 0; j < 4; ++j) {
        int row = wv * 32 + j * 8 + (lane >> 3);
        int m = mt * GBM + row; if (m >= cnt) m = cnt - 1;
        gA[j] = hbuf + (size_t)(hbase + m) * HDIM + kcL;
        gB[j] = W2T + ((size_t)e * DDIM + nbase + row) * HDIM + kcL;
    }
    int fr = lane & 15, fq = lane >> 4;
    int wm = (wv & 1) * 64, wn = (wv >> 1) * 64;

    floatx4 acc[4][4];
#pragma unroll
    for (int i = 0; i < 4; ++i)
#pragma unroll
        for (int j = 0; j < 4; ++j) acc[i][j] = (floatx4){0.f, 0.f, 0.f, 0.f};

#pragma unroll
    for (int j = 0; j < 4; ++j)
        gl_lds16(gA[j], &As[0][((wv * 4 + j) * 64 + lane) * 8]);
#pragma unroll
    for (int j = 0; j < 4; ++j)
        gl_lds16(gB[j], &Bs[0][((wv * 4 + j) * 64 + lane) * 8]);

    const int NK = HDIM / GBK;
    for (int i = 0; i < NK; ++i) {
        int cur = i & 1, nxt = cur ^ 1;
        __syncthreads();
        if (i + 1 < NK) {
            int k0 = (i + 1) * GBK;
#pragma unroll
            for (int j = 0; j < 4; ++j)
                gl_lds16(gA[j] + k0, &As[nxt][((wv * 4 + j) * 64 + lane) * 8]);
#pragma unroll
            for (int j = 0; j < 4; ++j)
                gl_lds16(gB[j] + k0, &Bs[nxt][((wv * 4 + j) * 64 + lane) * 8]);
        }
#pragma unroll
        for (int ks = 0; ks < 2; ++ks) {
            short8 af[4], bfr[4];
#pragma unroll
            for (int mi = 0; mi < 4; ++mi) {
                int row = wm + mi * 16 + fr;
                int kcs = (ks * 4 + fq) ^ (row & 7);
                af[mi] = *(const short8*)&As[cur][row * GBK + kcs * 8];
            }
#pragma unroll
            for (int ni = 0; ni < 4; ++ni) {
                int row = wn + ni * 16 + fr;
                int kcs = (ks * 4 + fq) ^ (row & 7);
                bfr[ni] = *(const short8*)&Bs[cur][row * GBK + kcs * 8];
            }
#pragma unroll
            for (int mi = 0; mi < 4; ++mi)
#pragma unroll
                for (int ni = 0; ni < 4; ++ni)
                    acc[mi][ni] = __builtin_amdgcn_mfma_f32_16x16x32_bf16(
                        af[mi], bfr[ni], acc[mi][ni], 0, 0, 0);
        }
    }

#pragma unroll
    for (int mi = 0; mi < 4; ++mi) {
#pragma unroll
        for (int r = 0; r < 4; ++r) {
            int row = wm + mi * 16 + fq * 4 + r;
            int m = mt * GBM + row;
            if (m < cnt) {
                size_t ro = (size_t)(hbase + m) * DDIM + nbase + wn;
#pragma unroll
                for (int ni = 0; ni < 4; ++ni)
                    ybuf[ro + ni * 16 + fr] = f2bf(acc[mi][ni][r]);
            }
        }
    }
}

// ---------------------------------------------------------------------------
// combine: out[t] = w0 * y[slot0] + w1 * y[slot1]  (writes every element,
// so no out-memset needed).
// ---------------------------------------------------------------------------
__global__ __launch_bounds__(256) void combine_kernel(
    const unsigned short* __restrict__ ybuf, const int* __restrict__ offsets,
    const int4* __restrict__ tinfo, const float2* __restrict__ wcomb,
    float* __restrict__ out)
{
    int t = blockIdx.x;
    int4   ti = tinfo[t];
    float2 w  = wcomb[t];
    int s0 = offsets[ti.x] + ti.y;
    int s1 = offsets[ti.z] + ti.w;
    const ushort4* y0 = (const ushort4*)(ybuf + (size_t)s0 * DDIM);
    const ushort4* y1 = (const ushort4*)(ybuf + (size_t)s1 * DDIM);
    float4* op = (float4*)(out + (size_t)t * DDIM);
#pragma unroll
    for (int i = 0; i < 2; ++i) {
        int c = threadIdx.x + i * 256;
        ushort4 a = y0[c], b = y1[c];
        float4 r;
        r.x = w.x * bf2f(a.x) + w.y * bf2f(b.x);
        r.y = w.x * bf2f(a.y) + w.y * bf2f(b.y);
        r.z = w.x * bf2f(a.z) + w.y * bf2f(b.z);
        r.w = w.x * bf2f(a.w) + w.y * bf2f(b.w);
        op[c] = r;
    }
}

// ---------------------------------------------------------------------------
// Workspace layout (bytes):
//   0         counts[16]
//   256       offsets[17]
//   512       ntiles + tile_e[80] + tile_mt[80]
//   2048      tok_list 16*4096*4      = 256 KB
//   264192    tinfo    4096*16        = 64 KB
//   329728    wcomb    4096*8         = 32 KB
//   524288    xbf      4096*2048*2    = 16 MB
//   17301504  hbuf     8192*1024*2    = 16 MB
//   34078720  ybuf     8192*2048*2    = 32 MB
//   67633152  W1T      16*1024*2048*2 = 64 MB
//   134742016 W2T      16*2048*1024*2 = 64 MB  -> total ~192.5 MB
// ---------------------------------------------------------------------------
extern "C" void kernel_launch(void* const* d_in, const int* in_sizes, int n_in,
                              void* d_out, int out_size, void* d_ws, size_t ws_size,
                              hipStream_t stream)
{
    const float* x    = (const float*)d_in[0];
    const float* Wg   = (const float*)d_in[1];
    const float* bias = (const float*)d_in[2];
    const float* W1   = (const float*)d_in[3];
    const float* W2   = (const float*)d_in[4];
    float* out = (float*)d_out;

    char* ws = (char*)d_ws;
    int*            counts   = (int*)(ws + 0);
    int*            offsets  = (int*)(ws + 256);
    int*            ntiles   = (int*)(ws + 512);
    int*            tile_e   = (int*)(ws + 512 + 4);
    int*            tile_mt  = (int*)(ws + 512 + 4 + MAX_TILES * 4);
    int*            tok_list = (int*)(ws + 2048);
    int4*           tinfo    = (int4*)(ws + 264192);
    float2*         wcomb    = (float2*)(ws + 329728);
    unsigned short* xbf      = (unsigned short*)(ws + 524288);
    unsigned short* hbuf     = (unsigned short*)(ws + 17301504);
    unsigned short* ybuf     = (unsigned short*)(ws + 34078720);
    unsigned short* W1T      = (unsigned short*)(ws + 67633152);
    unsigned short* W2T      = (unsigned short*)(ws + 134742016);

    hipMemsetAsync(counts, 0, 64, stream);

    prep_kernel<<<dim3(16, 32, 34), 256, 0, stream>>>(
        x, Wg, bias, W1, W2, W1T, W2T, counts, tok_list, tinfo, wcomb, xbf);
    scan_kernel<<<1, 64, 0, stream>>>(counts, offsets, ntiles, tile_e, tile_mt);
    up_gemm<<<dim3(MAX_TILES, HDIM / GBN), 256, 0, stream>>>(
        xbf, W1T, counts, offsets, ntiles, tile_e, tile_mt, tok_list, hbuf);
    down_gemm<<<dim3(MAX_TILES, DDIM / GBN), 256, 0, stream>>>(
        hbuf, W2T, counts, offsets, ntiles, tile_e, tile_mt, ybuf);
    combine_kernel<<<T_TOK, 256, 0, stream>>>(ybuf, offsets, tinfo, wcomb, out);
}